// Round 6
// baseline (669.085 us; speedup 1.0000x reference)
//
#include <hip/hip_runtime.h>
#include <math.h>

using s16x8  = __attribute__((ext_vector_type(8)))  short;
using f32x16 = __attribute__((ext_vector_type(16))) float;

#define BB 8
#define NN 4096
#define LL 32
#define DD 64
#define SS 64
#define NLV 2

// ws layout (float indices)
#define WEXT_OFF 0                      // [2][64][224] fp32 combined weights
#define BIAS_OFF 28672                  // [2][224]
#define WVEC_OFF 29120                  // [2][64]  w_l = oW @ (rW @ fW_seg)
#define SIG_OFF  29248                  // [2] sigma_l
#define BETA_OFF 29250                  // [2] beta_l
#define C0_OFF   29252                  // [2] rb.fWseg partials
#define FRAG_OFF 29256                  // frag base, byte 117024, 16B aligned
// byte layout inside frag region:
//   [0, 49152)        : LDS-bound frags  [l][nt'(6)][ks(4)] * 1024B   (a0,a1,b0,b1,c0,c1)
//   [49152, 57344)    : xm frags         [l][ks(4)] * 1024B           (global-read)
#define FRAG_LDS_BYTES 49152
#define XM_BYTE_OFF    49152

// ------------------------------------------------------------------
// prep1: Wext = [lpW@pW_a | lpW@pW_b | rowmean(lpW) x32 | lpW@pW_c] (64x224/level)
//        biasext + collapsed epilogue vectors/scalars.
// ------------------------------------------------------------------
__global__ void prep1(const float* __restrict__ lpW, const float* __restrict__ lpb,
                      const float* __restrict__ pW,  const float* __restrict__ pb,
                      const float* __restrict__ oW,  const float* __restrict__ ob,
                      const float* __restrict__ rW,  const float* __restrict__ rb,
                      const float* __restrict__ fW,  float* __restrict__ ws) {
    __shared__ float q[64];
    int blk = blockIdx.x;
    int d = threadIdx.x;                 // 0..63
    if (blk < 2 * 224) {
        int l = blk / 224, j = blk % 224;
        const float* lpWl = lpW + l * 64 * 64;
        const float* pWl  = pW  + l * 64 * 192;
        float wv;
        if (j < 128) {                   // a (0-63) and b (64-127) columns
            int col = j;
            float acc = 0.f;
            for (int e = 0; e < 64; ++e) acc = fmaf(lpWl[d * 64 + e], pWl[e * 192 + col], acc);
            wv = acc;
            if (d == 0) {
                float bb = pb[l * 192 + col];
                for (int e = 0; e < 64; ++e) bb = fmaf(lpb[l * 64 + e], pWl[e * 192 + col], bb);
                ws[BIAS_OFF + l * 224 + j] = bb;
            }
        } else if (j < 160) {            // xm columns: v replicated x32
            float s = 0.f;
            for (int e = 0; e < 64; ++e) s += lpWl[d * 64 + e];
            wv = s * (1.f / 64.f);
            if (d == 0) {
                float ss = 0.f;
                for (int e = 0; e < 64; ++e) ss += lpb[l * 64 + e];
                ws[BIAS_OFF + l * 224 + j] = ss * (1.f / 64.f);
            }
        } else {                         // c columns (pW cols 128-191)
            int col = j - 32;
            float acc = 0.f;
            for (int e = 0; e < 64; ++e) acc = fmaf(lpWl[d * 64 + e], pWl[e * 192 + col], acc);
            wv = acc;
            if (d == 0) {
                float bb = pb[l * 192 + col];
                for (int e = 0; e < 64; ++e) bb = fmaf(lpb[l * 64 + e], pWl[e * 192 + col], bb);
                ws[BIAS_OFF + l * 224 + j] = bb;
            }
        }
        ws[WEXT_OFF + (l * 64 + d) * 224 + j] = wv;
    } else {
        int l = blk - 2 * 224;           // 0..1
        float qv = 0.f;
        for (int j2 = 0; j2 < 64; ++j2) qv = fmaf(rW[l * 4096 + d * 64 + j2], fW[l * 64 + j2], qv);
        q[d] = qv;
        __syncthreads();
        float wv = 0.f;
        for (int s = 0; s < 64; ++s) wv = fmaf(oW[l * 4096 + d * 64 + s], q[s], wv);
        ws[WVEC_OFF + l * 64 + d] = wv;
        if (d == 0) { float s = 0.f; for (int i = 0; i < 64; ++i) s += q[i];               ws[SIG_OFF  + l] = s; }
        if (d == 1) { float s = 0.f; for (int i = 0; i < 64; ++i) s += ob[l*64+i] * q[i];  ws[BETA_OFF + l] = s; }
        if (d == 2) { float s = 0.f; for (int i = 0; i < 64; ++i) s += rb[l*64+i] * fW[l*64+i]; ws[C0_OFF + l] = s; }
    }
}

// ------------------------------------------------------------------
// prep2: pack Wext into RNE bf16 B-operand fragments.
// B layout (32x32x16): lane holds B[k][col], col=lane&31,
//   k = ks*16 + 4*(lane>>5) + (i&3) + 8*(i>>2)
// nt 0..6 over Wext columns; nt==4 (xm) goes to the global-read region,
// others (remapped 0..5) go to the LDS-staged region.
// ------------------------------------------------------------------
__global__ void prep2(float* __restrict__ ws) {
    int blk = blockIdx.x;                // l*28 + nt*4 + ks
    int l = blk / 28, r = blk % 28, nt = r / 4, ks = r % 4;
    int lane = threadIdx.x;
    const float* W = ws + WEXT_OFF + l * 64 * 224;
    s16x8 vh;
#pragma unroll
    for (int i = 0; i < 8; ++i) {
        int k   = ks * 16 + ((lane >> 5) << 2) + (i & 3) + ((i >> 2) << 3);
        int col = nt * 32 + (lane & 31);
        unsigned u = __float_as_uint(W[k * 224 + col]);
        unsigned rn = u + 0x7fffu + ((u >> 16) & 1u);   // RNE to bf16
        vh[i] = (short)(rn >> 16);
    }
    size_t dst;
    if (nt == 4) {
        dst = (size_t)XM_BYTE_OFF + ((size_t)l * 4 + ks) * 1024;
    } else {
        int ntp = (nt < 4) ? nt : nt - 1;               // a0,a1,b0,b1,c0,c1
        dst = (((size_t)l * 6 + ntp) * 4 + ks) * 1024;
    }
    char* base = reinterpret_cast<char*>(ws) + (size_t)FRAG_OFF * 4 + dst + lane * 16;
    *reinterpret_cast<s16x8*>(base) = vh;
}

// ------------------------------------------------------------------
// main: 1 wave per (b,n) pair; 8 waves/block; 48KB LDS -> 3 blocks/CU.
// 1-term RNE bf16 A and B. Tree-combined scan (only h31 needed).
// ------------------------------------------------------------------
#define BFRD(l, ntp, ks) (*reinterpret_cast<const s16x8*>(smem + ((((l)*6+(ntp))*4+(ks)))*1024 + lane16))

#define ACCINIT(acc, bval) do { float _b = (bval); _Pragma("unroll") \
    for (int _r = 0; _r < 16; ++_r) acc[_r] = _b; } while (0)

// two tiles interleaved for MFMA ILP (ntp = remapped LDS indices)
#define MMP(l, ntA, ntB, accA, accB) do { _Pragma("unroll") \
    for (int ks = 0; ks < 4; ++ks) { \
        s16x8 bA = BFRD(l, ntA, ks), bB = BFRD(l, ntB, ks); \
        accA = __builtin_amdgcn_mfma_f32_32x32x16_bf16(Ah[ks], bA, accA, 0, 0, 0); \
        accB = __builtin_amdgcn_mfma_f32_32x32x16_bf16(Ah[ks], bB, accB, 0, 0, 0); \
    } } while (0)

// xm tile: B-frags straight from global (8KB region, L1-resident)
#define MX1G(l, acc) do { _Pragma("unroll") \
    for (int ks = 0; ks < 4; ++ks) { \
        s16x8 b = FXM[((l)*4+ks)*64 + lane]; \
        acc = __builtin_amdgcn_mfma_f32_32x32x16_bf16(Ah[ks], b, acc, 0, 0, 0); \
    } } while (0)

__global__ __launch_bounds__(512, 6) void mlm_mfma(
    const float* __restrict__ p_seq, const float* __restrict__ fb,
    const float* __restrict__ ws, float* __restrict__ out) {

    __shared__ __align__(16) char smem[FRAG_LDS_BYTES];
    const int tid  = threadIdx.x;
    const int lane = tid & 63;
    const int wv   = tid >> 6;
    const int pair = blockIdx.x * 8 + wv;
    const int lane16 = lane * 16;
    const int row  = lane & 31;            // A-operand row = timestep t
    const int kofs = (lane >> 5) * 4;

    const s16x8* __restrict__ FXM = reinterpret_cast<const s16x8*>(
        reinterpret_cast<const char*>(ws) + (size_t)FRAG_OFF * 4 + XM_BYTE_OFF);

    {   // stage LDS-bound frags (48 KB, 512 thr x 6 float4)
        const float4* src = reinterpret_cast<const float4*>(
            reinterpret_cast<const char*>(ws) + (size_t)FRAG_OFF * 4);
        float4* dst = reinterpret_cast<float4*>(smem);
#pragma unroll
        for (int it = 0; it < 6; ++it) dst[tid + it * 512] = src[tid + it * 512];
    }

    // ---- A fragments: RNE bf16 of X rows (1-term) ----
    s16x8 Ah[4];
    {
        const float* X = p_seq + (size_t)pair * (LL * DD) + row * 64 + kofs;
#pragma unroll
        for (int ks = 0; ks < 4; ++ks) {
            const float4 v0 = *reinterpret_cast<const float4*>(X + ks * 16);
            const float4 v1 = *reinterpret_cast<const float4*>(X + ks * 16 + 8);
            float f[8] = {v0.x, v0.y, v0.z, v0.w, v1.x, v1.y, v1.z, v1.w};
#pragma unroll
            for (int i = 0; i < 8; ++i) {
                unsigned u = __float_as_uint(f[i]);
                unsigned rn = u + 0x7fffu + ((u >> 16) & 1u);   // RNE to bf16
                Ah[ks][i] = (short)(rn >> 16);
            }
        }
    }
    __syncthreads();

    const int myhalf = lane >> 5;
    // tree scan: t = (r&3) + 8*(r>>2) + 4*half. Only h31 needed; affine maps
    // compose: (A,U) per 4-block, combine halves via shfl, then 2 local levels.
    auto scan_h = [&](const f32x16& aT, const f32x16& bT, const f32x16& xmT) -> float {
        float Ak[4], Uk[4];
#pragma unroll
        for (int k = 0; k < 4; ++k) {
            const int rb = k * 4;
            float s0 = __builtin_amdgcn_rcpf(1.f + __expf(-aT[rb + 0]));
            float s1 = __builtin_amdgcn_rcpf(1.f + __expf(-aT[rb + 1]));
            float s2 = __builtin_amdgcn_rcpf(1.f + __expf(-aT[rb + 2]));
            float s3 = __builtin_amdgcn_rcpf(1.f + __expf(-aT[rb + 3]));
            float u0 = bT[rb + 0] * xmT[rb + 0];
            float u1 = bT[rb + 1] * xmT[rb + 1];
            float u2 = bT[rb + 2] * xmT[rb + 2];
            float u3 = bT[rb + 3] * xmT[rb + 3];
            float A = (s0 * s1) * (s2 * s3);
            float U = fmaf(fmaf(fmaf(u0, s1, u1), s2, u2), s3, u3);
            // combine the two lane-halves (half0 = earlier 4 steps)
            float Ao = __shfl_xor(A, 32);
            float Uo = __shfl_xor(U, 32);
            float Ue = myhalf ? Uo : U;    // earlier U
            float Ul = myhalf ? U  : Uo;   // later U
            float Al = myhalf ? A  : Ao;   // later A
            Ak[k] = A * Ao;
            Uk[k] = fmaf(Ue, Al, Ul);
        }
        float U01 = fmaf(Uk[0], Ak[1], Uk[1]);     // t 0..15
        float U23 = fmaf(Uk[2], Ak[3], Uk[3]);     // t 16..31
        float A23 = Ak[2] * Ak[3];
        return fmaf(U01, A23, U23);                // h31 (h-1 = 0)
    };

    float yp = 0.f;
    const float c0sum = ws[C0_OFF] + ws[C0_OFF + 1] + fb[0];

#pragma unroll 1
    for (int l = 0; l < 2; ++l) {
        const float* bias = ws + BIAS_OFF + l * 224;
        const int col = lane & 31;

        f32x16 xmT; ACCINIT(xmT, bias[128 + col]);   // xm replicated columns
        MX1G(l, xmT);

        f32x16 tA, tB;
        ACCINIT(tA, bias[0 + col]);   ACCINIT(tB, bias[64 + col]);   // a s0-31, b s0-31
        MMP(l, 0, 2, tA, tB);
        float h0 = scan_h(tA, tB, xmT);

        ACCINIT(tA, bias[32 + col]);  ACCINIT(tB, bias[96 + col]);   // a s32-63, b s32-63
        MMP(l, 1, 3, tA, tB);
        float h1 = scan_h(tA, tB, xmT);

        const float xm31 = xmT[15];
        ACCINIT(tA, bias[160 + col]); ACCINIT(tB, bias[192 + col]);  // c tiles
        MMP(l, 4, 5, tA, tB);

        // epilogue: reg15 in upper half = t=31
        if (lane >= 32) {
            float x0 = tA[15] * h0;                    // c[s=lane-32] * h0[s]
            float x1 = tB[15] * h1;                    // c[s=lane]    * h1[s]
            float g0 = 0.5f * x0 * (1.f + erff(x0 * 0.70710678118654752440f));
            float g1 = 0.5f * x1 * (1.f + erff(x1 * 0.70710678118654752440f));
            float term = g0 * ws[WVEC_OFF + l * 64 + (lane - 32)]
                       + g1 * ws[WVEC_OFF + l * 64 + lane];
            if (lane == 32) term += xm31 * ws[SIG_OFF + l] + ws[BETA_OFF + l];
            yp += term;
        }
    }

#pragma unroll
    for (int off = 16; off >= 1; off >>= 1) yp += __shfl_xor(yp, off);
    if (lane == 32) out[pair] = yp + c0sum;
}

extern "C" void kernel_launch(void* const* d_in, const int* in_sizes, int n_in,
                              void* d_out, int out_size, void* d_ws, size_t ws_size,
                              hipStream_t stream) {
    const float* p_seq = (const float*)d_in[0];
    const float* lp_W  = (const float*)d_in[1];
    const float* lp_b  = (const float*)d_in[2];
    const float* pW    = (const float*)d_in[3];
    const float* pb    = (const float*)d_in[4];
    const float* oW    = (const float*)d_in[5];
    const float* ob    = (const float*)d_in[6];
    const float* rW    = (const float*)d_in[7];
    const float* rb    = (const float*)d_in[8];
    const float* fW    = (const float*)d_in[9];
    const float* fb    = (const float*)d_in[10];

    float* ws  = (float*)d_ws;
    float* out = (float*)d_out;

    prep1<<<2 * 224 + 2, 64, 0, stream>>>(lp_W, lp_b, pW, pb, oW, ob, rW, rb, fW, ws);
    prep2<<<2 * 28, 64, 0, stream>>>(ws);

    const int pairs = BB * NN;               // 32768, 8 pairs per block
    mlm_mfma<<<pairs / 8, 512, 0, stream>>>(p_seq, fb, ws, out);
}

// Round 7
// 104.260 us; speedup vs baseline: 6.4175x; 6.4175x over previous
//
#include <hip/hip_runtime.h>
#include <math.h>

using s16x8  = __attribute__((ext_vector_type(8)))  short;
using f32x16 = __attribute__((ext_vector_type(16))) float;

#define BB 8
#define NN 4096
#define LL 32
#define DD 64
#define SS 64
#define NLV 2

// ws layout (float indices)
#define WEXT_OFF 0                      // [2][64][224] fp32 combined weights
#define BIAS_OFF 28672                  // [2][224]
#define WVEC_OFF 29120                  // [2][64]  w_l = oW @ (rW @ fW_seg)
#define SIG_OFF  29248                  // [2] sigma_l
#define BETA_OFF 29250                  // [2] beta_l
#define C0_OFF   29252                  // [2] rb.fWseg partials
#define FRAG_OFF 29256                  // frag base, byte 117024, 16B aligned
// byte layout inside frag region:
//   [0, 49152)        : LDS-bound frags  [l][nt'(6)][ks(4)] * 1024B   (a0,a1,b0,b1,c0,c1)
//   [49152, 57344)    : xm frags         [l][ks(4)] * 1024B           (global-read)
#define FRAG_LDS_BYTES 49152
#define XM_BYTE_OFF    49152

// ------------------------------------------------------------------
// prep1: Wext = [lpW@pW_a | lpW@pW_b | rowmean(lpW) x32 | lpW@pW_c] (64x224/level)
//        biasext + collapsed epilogue vectors/scalars.
// ------------------------------------------------------------------
__global__ void prep1(const float* __restrict__ lpW, const float* __restrict__ lpb,
                      const float* __restrict__ pW,  const float* __restrict__ pb,
                      const float* __restrict__ oW,  const float* __restrict__ ob,
                      const float* __restrict__ rW,  const float* __restrict__ rb,
                      const float* __restrict__ fW,  float* __restrict__ ws) {
    __shared__ float q[64];
    int blk = blockIdx.x;
    int d = threadIdx.x;                 // 0..63
    if (blk < 2 * 224) {
        int l = blk / 224, j = blk % 224;
        const float* lpWl = lpW + l * 64 * 64;
        const float* pWl  = pW  + l * 64 * 192;
        float wv;
        if (j < 128) {                   // a (0-63) and b (64-127) columns
            int col = j;
            float acc = 0.f;
            for (int e = 0; e < 64; ++e) acc = fmaf(lpWl[d * 64 + e], pWl[e * 192 + col], acc);
            wv = acc;
            if (d == 0) {
                float bb = pb[l * 192 + col];
                for (int e = 0; e < 64; ++e) bb = fmaf(lpb[l * 64 + e], pWl[e * 192 + col], bb);
                ws[BIAS_OFF + l * 224 + j] = bb;
            }
        } else if (j < 160) {            // xm columns: v replicated x32
            float s = 0.f;
            for (int e = 0; e < 64; ++e) s += lpWl[d * 64 + e];
            wv = s * (1.f / 64.f);
            if (d == 0) {
                float ss = 0.f;
                for (int e = 0; e < 64; ++e) ss += lpb[l * 64 + e];
                ws[BIAS_OFF + l * 224 + j] = ss * (1.f / 64.f);
            }
        } else {                         // c columns (pW cols 128-191)
            int col = j - 32;
            float acc = 0.f;
            for (int e = 0; e < 64; ++e) acc = fmaf(lpWl[d * 64 + e], pWl[e * 192 + col], acc);
            wv = acc;
            if (d == 0) {
                float bb = pb[l * 192 + col];
                for (int e = 0; e < 64; ++e) bb = fmaf(lpb[l * 64 + e], pWl[e * 192 + col], bb);
                ws[BIAS_OFF + l * 224 + j] = bb;
            }
        }
        ws[WEXT_OFF + (l * 64 + d) * 224 + j] = wv;
    } else {
        int l = blk - 2 * 224;           // 0..1
        float qv = 0.f;
        for (int j2 = 0; j2 < 64; ++j2) qv = fmaf(rW[l * 4096 + d * 64 + j2], fW[l * 64 + j2], qv);
        q[d] = qv;
        __syncthreads();
        float wv = 0.f;
        for (int s = 0; s < 64; ++s) wv = fmaf(oW[l * 4096 + d * 64 + s], q[s], wv);
        ws[WVEC_OFF + l * 64 + d] = wv;
        if (d == 0) { float s = 0.f; for (int i = 0; i < 64; ++i) s += q[i];               ws[SIG_OFF  + l] = s; }
        if (d == 1) { float s = 0.f; for (int i = 0; i < 64; ++i) s += ob[l*64+i] * q[i];  ws[BETA_OFF + l] = s; }
        if (d == 2) { float s = 0.f; for (int i = 0; i < 64; ++i) s += rb[l*64+i] * fW[l*64+i]; ws[C0_OFF + l] = s; }
    }
}

// ------------------------------------------------------------------
// prep2: pack Wext into RNE bf16 B-operand fragments.
// B layout (32x32x16): lane holds B[k][col], col=lane&31,
//   k = ks*16 + 4*(lane>>5) + (i&3) + 8*(i>>2)
// nt 0..6 over Wext columns; nt==4 (xm) goes to the global-read region,
// others (remapped 0..5) go to the LDS-staged region.
// ------------------------------------------------------------------
__global__ void prep2(float* __restrict__ ws) {
    int blk = blockIdx.x;                // l*28 + nt*4 + ks
    int l = blk / 28, r = blk % 28, nt = r / 4, ks = r % 4;
    int lane = threadIdx.x;
    const float* W = ws + WEXT_OFF + l * 64 * 224;
    s16x8 vh;
#pragma unroll
    for (int i = 0; i < 8; ++i) {
        int k   = ks * 16 + ((lane >> 5) << 2) + (i & 3) + ((i >> 2) << 3);
        int col = nt * 32 + (lane & 31);
        unsigned u = __float_as_uint(W[k * 224 + col]);
        unsigned rn = u + 0x7fffu + ((u >> 16) & 1u);   // RNE to bf16
        vh[i] = (short)(rn >> 16);
    }
    size_t dst;
    if (nt == 4) {
        dst = (size_t)XM_BYTE_OFF + ((size_t)l * 4 + ks) * 1024;
    } else {
        int ntp = (nt < 4) ? nt : nt - 1;               // a0,a1,b0,b1,c0,c1
        dst = (((size_t)l * 6 + ntp) * 4 + ks) * 1024;
    }
    char* base = reinterpret_cast<char*>(ws) + (size_t)FRAG_OFF * 4 + dst + lane * 16;
    *reinterpret_cast<s16x8*>(base) = vh;
}

// ------------------------------------------------------------------
// main: 1 wave per (b,n) pair; 8 waves/block; 48KB LDS -> 3 blocks/CU
// (24 waves/CU, LDS-limited). launch_bounds(512,4): R5-proven VGPR~60,
// NO spill — (512,6) compiled to VGPR 40 and spilled 1.6GB (R6 lesson).
// 1-term RNE bf16 A and B. Tree-combined scan (only h31 needed).
// ------------------------------------------------------------------
#define BFRD(l, ntp, ks) (*reinterpret_cast<const s16x8*>(smem + ((((l)*6+(ntp))*4+(ks)))*1024 + lane16))

#define ACCINIT(acc, bval) do { float _b = (bval); _Pragma("unroll") \
    for (int _r = 0; _r < 16; ++_r) acc[_r] = _b; } while (0)

// two tiles interleaved for MFMA ILP (ntp = remapped LDS indices)
#define MMP(l, ntA, ntB, accA, accB) do { _Pragma("unroll") \
    for (int ks = 0; ks < 4; ++ks) { \
        s16x8 bA = BFRD(l, ntA, ks), bB = BFRD(l, ntB, ks); \
        accA = __builtin_amdgcn_mfma_f32_32x32x16_bf16(Ah[ks], bA, accA, 0, 0, 0); \
        accB = __builtin_amdgcn_mfma_f32_32x32x16_bf16(Ah[ks], bB, accB, 0, 0, 0); \
    } } while (0)

// xm tile: B-frags straight from global (8KB region, L1-resident)
#define MX1G(l, acc) do { _Pragma("unroll") \
    for (int ks = 0; ks < 4; ++ks) { \
        s16x8 b = FXM[((l)*4+ks)*64 + lane]; \
        acc = __builtin_amdgcn_mfma_f32_32x32x16_bf16(Ah[ks], b, acc, 0, 0, 0); \
    } } while (0)

__global__ __launch_bounds__(512, 4) void mlm_mfma(
    const float* __restrict__ p_seq, const float* __restrict__ fb,
    const float* __restrict__ ws, float* __restrict__ out) {

    __shared__ __align__(16) char smem[FRAG_LDS_BYTES];
    const int tid  = threadIdx.x;
    const int lane = tid & 63;
    const int wv   = tid >> 6;
    const int pair = blockIdx.x * 8 + wv;
    const int lane16 = lane * 16;
    const int row  = lane & 31;            // A-operand row = timestep t
    const int kofs = (lane >> 5) * 4;

    const s16x8* __restrict__ FXM = reinterpret_cast<const s16x8*>(
        reinterpret_cast<const char*>(ws) + (size_t)FRAG_OFF * 4 + XM_BYTE_OFF);

    {   // stage LDS-bound frags (48 KB, 512 thr x 6 float4)
        const float4* src = reinterpret_cast<const float4*>(
            reinterpret_cast<const char*>(ws) + (size_t)FRAG_OFF * 4);
        float4* dst = reinterpret_cast<float4*>(smem);
#pragma unroll
        for (int it = 0; it < 6; ++it) dst[tid + it * 512] = src[tid + it * 512];
    }

    // ---- A fragments: RNE bf16 of X rows (1-term) ----
    s16x8 Ah[4];
    {
        const float* X = p_seq + (size_t)pair * (LL * DD) + row * 64 + kofs;
#pragma unroll
        for (int ks = 0; ks < 4; ++ks) {
            const float4 v0 = *reinterpret_cast<const float4*>(X + ks * 16);
            const float4 v1 = *reinterpret_cast<const float4*>(X + ks * 16 + 8);
            float f[8] = {v0.x, v0.y, v0.z, v0.w, v1.x, v1.y, v1.z, v1.w};
#pragma unroll
            for (int i = 0; i < 8; ++i) {
                unsigned u = __float_as_uint(f[i]);
                unsigned rn = u + 0x7fffu + ((u >> 16) & 1u);   // RNE to bf16
                Ah[ks][i] = (short)(rn >> 16);
            }
        }
    }
    __syncthreads();

    const int myhalf = lane >> 5;
    // tree scan: t = (r&3) + 8*(r>>2) + 4*half. Only h31 needed; affine maps
    // compose: (A,U) per 4-block, combine halves via shfl, then 2 local levels.
    auto scan_h = [&](const f32x16& aT, const f32x16& bT, const f32x16& xmT) -> float {
        float Ak[4], Uk[4];
#pragma unroll
        for (int k = 0; k < 4; ++k) {
            const int rb = k * 4;
            float s0 = __builtin_amdgcn_rcpf(1.f + __expf(-aT[rb + 0]));
            float s1 = __builtin_amdgcn_rcpf(1.f + __expf(-aT[rb + 1]));
            float s2 = __builtin_amdgcn_rcpf(1.f + __expf(-aT[rb + 2]));
            float s3 = __builtin_amdgcn_rcpf(1.f + __expf(-aT[rb + 3]));
            float u0 = bT[rb + 0] * xmT[rb + 0];
            float u1 = bT[rb + 1] * xmT[rb + 1];
            float u2 = bT[rb + 2] * xmT[rb + 2];
            float u3 = bT[rb + 3] * xmT[rb + 3];
            float A = (s0 * s1) * (s2 * s3);
            float U = fmaf(fmaf(fmaf(u0, s1, u1), s2, u2), s3, u3);
            // combine the two lane-halves (half0 = earlier 4 steps)
            float Ao = __shfl_xor(A, 32);
            float Uo = __shfl_xor(U, 32);
            float Ue = myhalf ? Uo : U;    // earlier U
            float Ul = myhalf ? U  : Uo;   // later U
            float Al = myhalf ? A  : Ao;   // later A
            Ak[k] = A * Ao;
            Uk[k] = fmaf(Ue, Al, Ul);
        }
        float U01 = fmaf(Uk[0], Ak[1], Uk[1]);     // t 0..15
        float U23 = fmaf(Uk[2], Ak[3], Uk[3]);     // t 16..31
        float A23 = Ak[2] * Ak[3];
        return fmaf(U01, A23, U23);                // h31 (h-1 = 0)
    };

    float yp = 0.f;
    const float c0sum = ws[C0_OFF] + ws[C0_OFF + 1] + fb[0];

#pragma unroll 1
    for (int l = 0; l < 2; ++l) {
        const float* bias = ws + BIAS_OFF + l * 224;
        const int col = lane & 31;

        f32x16 xmT; ACCINIT(xmT, bias[128 + col]);   // xm replicated columns
        MX1G(l, xmT);

        f32x16 tA, tB;
        ACCINIT(tA, bias[0 + col]);   ACCINIT(tB, bias[64 + col]);   // a s0-31, b s0-31
        MMP(l, 0, 2, tA, tB);
        float h0 = scan_h(tA, tB, xmT);

        ACCINIT(tA, bias[32 + col]);  ACCINIT(tB, bias[96 + col]);   // a s32-63, b s32-63
        MMP(l, 1, 3, tA, tB);
        float h1 = scan_h(tA, tB, xmT);

        const float xm31 = xmT[15];
        ACCINIT(tA, bias[160 + col]); ACCINIT(tB, bias[192 + col]);  // c tiles
        MMP(l, 4, 5, tA, tB);

        // epilogue: reg15 in upper half = t=31
        if (lane >= 32) {
            float x0 = tA[15] * h0;                    // c[s=lane-32] * h0[s]
            float x1 = tB[15] * h1;                    // c[s=lane]    * h1[s]
            float g0 = 0.5f * x0 * (1.f + erff(x0 * 0.70710678118654752440f));
            float g1 = 0.5f * x1 * (1.f + erff(x1 * 0.70710678118654752440f));
            float term = g0 * ws[WVEC_OFF + l * 64 + (lane - 32)]
                       + g1 * ws[WVEC_OFF + l * 64 + lane];
            if (lane == 32) term += xm31 * ws[SIG_OFF + l] + ws[BETA_OFF + l];
            yp += term;
        }
    }

#pragma unroll
    for (int off = 16; off >= 1; off >>= 1) yp += __shfl_xor(yp, off);
    if (lane == 32) out[pair] = yp + c0sum;
}

extern "C" void kernel_launch(void* const* d_in, const int* in_sizes, int n_in,
                              void* d_out, int out_size, void* d_ws, size_t ws_size,
                              hipStream_t stream) {
    const float* p_seq = (const float*)d_in[0];
    const float* lp_W  = (const float*)d_in[1];
    const float* lp_b  = (const float*)d_in[2];
    const float* pW    = (const float*)d_in[3];
    const float* pb    = (const float*)d_in[4];
    const float* oW    = (const float*)d_in[5];
    const float* ob    = (const float*)d_in[6];
    const float* rW    = (const float*)d_in[7];
    const float* rb    = (const float*)d_in[8];
    const float* fW    = (const float*)d_in[9];
    const float* fb    = (const float*)d_in[10];

    float* ws  = (float*)d_ws;
    float* out = (float*)d_out;

    prep1<<<2 * 224 + 2, 64, 0, stream>>>(lp_W, lp_b, pW, pb, oW, ob, rW, rb, fW, ws);
    prep2<<<2 * 28, 64, 0, stream>>>(ws);

    const int pairs = BB * NN;               // 32768, 8 pairs per block
    mlm_mfma<<<pairs / 8, 512, 0, stream>>>(p_seq, fb, ws, out);
}